// Round 2
// baseline (305.884 us; speedup 1.0000x reference)
//
#include <hip/hip_runtime.h>
#include <hip/hip_bf16.h>

typedef __bf16 bf16;
typedef __attribute__((ext_vector_type(4))) float f32x4;
typedef __attribute__((ext_vector_type(8))) bf16 bf16x8;
typedef __attribute__((ext_vector_type(2))) bf16 bf16x2;

#define NCAMS 6
#define NQ 6400
#define CH 256
#define NH 8
#define NL 3
#define NP 8
#define S_TOT 14784   // 64*176 + 32*88 + 16*44

#if __has_builtin(__builtin_amdgcn_fdot2_f32_bf16) && __has_builtin(__builtin_amdgcn_perm)
#define MSDA_DOT2 1
#else
#define MSDA_DOT2 0
#endif

// ---------------------------------------------------------------- K1: prep = projection + weight packs
// blocks 0..149: projection; blocks 150..285: pack Wvp (8192) / Woap (18432) / Wop (8192)
__global__ __launch_bounds__(256) void k_prep(
    const float* __restrict__ means, const float* __restrict__ cam2ego,
    const float* __restrict__ intrins, const float* __restrict__ post_rots,
    const float* __restrict__ post_trans, const int* __restrict__ img_h,
    const int* __restrict__ img_w,
    const float* __restrict__ W_val, const float* __restrict__ W_off,
    const float* __restrict__ W_attn, const float* __restrict__ W_out,
    float* __restrict__ coor, float* __restrict__ maskf,
    bf16* __restrict__ Wvp, bf16* __restrict__ Woap, bf16* __restrict__ Wop)
{
    int bid = blockIdx.x;
    if (bid < 150) {
        int idx = bid * 256 + threadIdx.x;
        if (idx >= NCAMS * NQ) return;
        int cam = idx / NQ, n = idx % NQ;
        float mx = means[n*3+0], my = means[n*3+1], mz = means[n*3+2];
        const float* M = cam2ego + cam*16;
        float R[3][3], t[3];
        #pragma unroll
        for (int r = 0; r < 3; r++) {
            #pragma unroll
            for (int c = 0; c < 3; c++) R[r][c] = M[r*4+c];
            t[r] = M[r*4+3];
        }
        float dx = mx - t[0], dy = my - t[1], dz = mz - t[2];
        float xc = R[0][0]*dx + R[1][0]*dy + R[2][0]*dz;
        float yc = R[0][1]*dx + R[1][1]*dy + R[2][1]*dz;
        float zc = R[0][2]*dx + R[1][2]*dy + R[2][2]*dz;
        const float* K = intrins + cam*9;
        float ix = K[0]*xc + K[1]*yc + K[2]*zc;
        float iy = K[3]*xc + K[4]*yc + K[5]*zc;
        float iz = K[6]*xc + K[7]*yc + K[8]*zc;
        float px = ix / (iz + 1e-4f), py = iy / (iz + 1e-4f), pz = iz;
        const float* P = post_rots + cam*9;
        const float* T = post_trans + cam*3;
        float vx = P[0]*px + P[1]*py + P[2]*pz + T[0];
        float vy = P[3]*px + P[4]*py + P[5]*pz + T[1];
        float vz = P[6]*px + P[7]*py + P[8]*pz + T[2];
        float cx = vx / (float)img_w[0];
        float cy = vy / (float)img_h[0];
        bool ok = (vz > 0.01f) && (cx > 0.f) && (cx < 1.f) && (cy > 0.f) && (cy < 1.f);
        coor[idx*2+0] = cx;
        coor[idx*2+1] = cy;
        maskf[idx] = ok ? 1.f : 0.f;
        return;
    }
    int flat = (bid - 150) * 256 + threadIdx.x;
    if (flat < 8192) {
        // Wvp: (kc*16+nf)*64+lane <- W_val[kc*32+q*8+j][nf*16+l15]
        int kc = flat >> 10, rem = flat & 1023;
        int nf = rem >> 6, lane = rem & 63;
        int q = lane >> 4, col = nf*16 + (lane & 15);
        bf16x8 v;
        #pragma unroll
        for (int j = 0; j < 8; j++) v[j] = (bf16)W_val[(size_t)(kc*32 + q*8 + j)*256 + col];
        *reinterpret_cast<bf16x8*>(Wvp + (size_t)flat*8) = v;
    } else if (flat < 26624) {
        // Woap: 576 logical cols = [W_off 0..383 | W_attn 384..575]
        int f2 = flat - 8192;
        int kc = f2 / (36*64), rem = f2 % (36*64);
        int nf = rem >> 6, lane = rem & 63;
        int q = lane >> 4, col = nf*16 + (lane & 15);
        bf16x8 v;
        #pragma unroll
        for (int j = 0; j < 8; j++) {
            int k = kc*32 + q*8 + j;
            float x = (col < 384) ? W_off[(size_t)k*384 + col] : W_attn[(size_t)k*192 + (col-384)];
            v[j] = (bf16)x;
        }
        *reinterpret_cast<bf16x8*>(Woap + (size_t)f2*8) = v;
    } else if (flat < 34816) {
        int f3 = flat - 26624;
        int kc = f3 >> 10, rem = f3 & 1023;
        int nf = rem >> 6, lane = rem & 63;
        int q = lane >> 4, col = nf*16 + (lane & 15);
        bf16x8 v;
        #pragma unroll
        for (int j = 0; j < 8; j++) v[j] = (bf16)W_out[(size_t)(kc*32 + q*8 + j)*256 + col];
        *reinterpret_cast<bf16x8*>(Wop + (size_t)f3*8) = v;
    }
}

// ---------------------------------------------------------------- K2: offsets + attn via MFMA (+softmax)
// 400 blocks x 16 queries. A-frags direct from global (feature rows are k-contiguous).
__global__ __launch_bounds__(256) void k_offattn2(
    const float* __restrict__ feature, const bf16* __restrict__ Woap,
    const float* __restrict__ b_off, const float* __restrict__ b_attn,
    float* __restrict__ offs, bf16* __restrict__ attn_out)
{
    __shared__ float lg[16][200];    // logits [m][192], padded
    int t = threadIdx.x, lane = t & 63, w = t >> 6;
    int q = lane >> 4, r16 = lane & 15;
    int n0 = blockIdx.x * 16;

    f32x4 acc[9];
    #pragma unroll
    for (int i = 0; i < 9; i++) acc[i] = (f32x4){0.f,0.f,0.f,0.f};

    const float* arow = feature + (size_t)(n0 + r16)*CH;
    for (int kc = 0; kc < 8; kc++) {
        f32x4 a0 = *reinterpret_cast<const f32x4*>(arow + kc*32 + q*8);
        f32x4 a1 = *reinterpret_cast<const f32x4*>(arow + kc*32 + q*8 + 4);
        bf16x8 afr;
        #pragma unroll
        for (int i = 0; i < 4; i++) { afr[i] = (bf16)a0[i]; afr[4+i] = (bf16)a1[i]; }
        #pragma unroll
        for (int nf9 = 0; nf9 < 9; nf9++) {
            bf16x8 bfr = *reinterpret_cast<const bf16x8*>(Woap + ((size_t)(kc*36 + w*9 + nf9)*64 + lane)*8);
            acc[nf9] = __builtin_amdgcn_mfma_f32_16x16x32_bf16(afr, bfr, acc[nf9], 0, 0, 0);
        }
    }
    #pragma unroll
    for (int nf9 = 0; nf9 < 9; nf9++) {
        int nfg = w*9 + nf9;
        int nglob = nfg*16 + r16;
        if (nfg < 24) {                       // offsets (wave-uniform branch)
            float bias = b_off[nglob];
            #pragma unroll
            for (int r = 0; r < 4; r++)
                offs[(size_t)(n0 + q*4 + r)*384 + nglob] = acc[nf9][r] + bias;
        } else {                              // attn logits -> LDS
            int la = nglob - 384;
            float bias = b_attn[la];
            #pragma unroll
            for (int r = 0; r < 4; r++)
                lg[q*4 + r][la] = acc[nf9][r] + bias;
        }
    }
    __syncthreads();
    if (t < 128) {
        int m = t >> 3, h = t & 7;
        const float* L = &lg[m][h*24];
        float mx = -1e30f;
        #pragma unroll
        for (int j = 0; j < 24; j++) mx = fmaxf(mx, L[j]);
        float e[24]; float s = 0.f;
        #pragma unroll
        for (int j = 0; j < 24; j++) { e[j] = __expf(L[j] - mx); s += e[j]; }
        float inv = 1.f / s;
        #pragma unroll
        for (int j = 0; j < 24; j++) attn_out[(size_t)(n0+m)*192 + h*24 + j] = (bf16)(e[j]*inv);
    }
}

// ---------------------------------------------------------------- K3: value projection GEMM (MFMA bf16)
// value layout: [cam][head][pos][32ch]  (bf16)
__global__ __launch_bounds__(256) void k_valproj(
    const float* __restrict__ f0, const float* __restrict__ f1, const float* __restrict__ f2,
    const float* __restrict__ cams_embeds, const float* __restrict__ level_embeds,
    const bf16* __restrict__ Wvp, const float* __restrict__ b_val, bf16* __restrict__ value)
{
    __shared__ alignas(16) bf16 A[64][48];    // [m][k], padded row 48 (6144 B)
    __shared__ alignas(16) bf16 Cst[16][256]; // epilogue staging stripe (8192 B)
    int bi = blockIdx.x;
    int cam = bi / 231, mb = bi % 231;
    int lvl, local0, HW;
    const float* fp;
    if (mb < 176)      { lvl = 0; local0 = mb*64;        fp = f0; HW = 11264; }
    else if (mb < 220) { lvl = 1; local0 = (mb-176)*64;  fp = f1; HW = 2816;  }
    else               { lvl = 2; local0 = (mb-220)*64;  fp = f2; HW = 704;   }
    int pos0 = (lvl == 0 ? 0 : (lvl == 1 ? 11264 : 14080)) + local0;
    const float* featbase = fp + (size_t)cam*CH*HW + local0;

    int t = threadIdx.x;
    int lane = t & 63, w = t >> 6;
    int kk = t >> 3;            // 0..31 (channel within chunk)
    int m8 = (t & 7) * 8;       // m start
    int q = lane >> 4, r16 = lane & 15;

    f32x4 acc[4][4];
    #pragma unroll
    for (int i = 0; i < 4; i++)
        #pragma unroll
        for (int j = 0; j < 4; j++) acc[i][j] = (f32x4){0.f,0.f,0.f,0.f};

    for (int kc = 0; kc < 8; kc++) {
        __syncthreads();
        int kg = kc*32 + kk;
        float e = cams_embeds[cam*CH + kg] + level_embeds[lvl*CH + kg];
        f32x4 v0 = *reinterpret_cast<const f32x4*>(featbase + (size_t)kg*HW + m8);
        f32x4 v1 = *reinterpret_cast<const f32x4*>(featbase + (size_t)kg*HW + m8 + 4);
        #pragma unroll
        for (int i = 0; i < 4; i++) A[m8+i][kk]   = (bf16)(v0[i] + e);
        #pragma unroll
        for (int i = 0; i < 4; i++) A[m8+4+i][kk] = (bf16)(v1[i] + e);
        __syncthreads();

        bf16x8 bfr[4];
        #pragma unroll
        for (int nf = 0; nf < 4; nf++) {
            int nfg = w*4 + nf;
            bfr[nf] = *reinterpret_cast<const bf16x8*>(Wvp + ((size_t)(kc*16 + nfg)*64 + lane)*8);
        }
        #pragma unroll
        for (int mf = 0; mf < 4; mf++) {
            bf16x8 afr = *reinterpret_cast<const bf16x8*>(&A[mf*16 + r16][q*8]);
            #pragma unroll
            for (int nf = 0; nf < 4; nf++)
                acc[mf][nf] = __builtin_amdgcn_mfma_f32_16x16x32_bf16(afr, bfr[nf], acc[mf][nf], 0, 0, 0);
        }
    }
    // epilogue, per 16-row stripe -> LDS -> coalesced 16B stores
    int orow = t >> 4;                // 0..15
    int ocol = (t & 15) * 16;         // 0..240 step 16
    int ohead = ocol >> 5, och = ocol & 31;
    #pragma unroll
    for (int mf = 0; mf < 4; mf++) {
        __syncthreads();
        #pragma unroll
        for (int nf = 0; nf < 4; nf++) {
            int c = w*64 + nf*16 + r16;
            float bv = b_val[c];
            #pragma unroll
            for (int r = 0; r < 4; r++)
                Cst[q*4 + r][c] = (bf16)(acc[mf][nf][r] + bv);
        }
        __syncthreads();
        int srow = pos0 + mf*16 + orow;
        bf16* dst = value + ((size_t)(cam*NH + ohead)*S_TOT + srow)*32 + och;
        const f32x4* src = reinterpret_cast<const f32x4*>(&Cst[orow][ocol]);
        f32x4 x0 = src[0], x1 = src[1];
        reinterpret_cast<f32x4*>(dst)[0] = x0;
        reinterpret_cast<f32x4*>(dst)[1] = x1;
    }
}

// ---------------------------------------------------------------- K4: MSDA gather
// Phase 1: sampling params for ALL 6 cams x 8 heads x 24 (lvl,pt) -> LDS, mask folded into weights.
// s_o packed as int2 {o00|dxbit, o01}: x1 = x0 + dx with dx in {0,64} bytes packed into bit 0
// (offsets are multiples of 64). LDS 27.6 KB -> 18.4 KB => 8 blocks/CU (occupancy cap 100%,
// was ~50% -- the kernel is latency-bound at VALUBusy 61%, so residency is the lever).
// Phase 2: uint4 (16B) gathers, 2 heads x 8 pts x 4 ch-groups per wave.
__global__ __launch_bounds__(256, 8) void k_msda(
    const float* __restrict__ coor, const float* __restrict__ offs,
    const bf16* __restrict__ attn, const bf16* __restrict__ value,
    const float* __restrict__ maskf, float* __restrict__ slots)
{
    // item = cam*192 + h*24 + lvl*8 + p
    __shared__ int2  s_o[NCAMS*192];     // {y0-row offset | dx bit, y1-row offset}  (9216 B)
#if MSDA_DOT2
    __shared__ uint2 s_w[NCAMS*192];     // packed bf16 {w00,w10},{w01,w11} (9216 B)
#else
    __shared__ f32x4 s_w[NCAMS*192];
#endif
    int n = blockIdx.x;
    int t = threadIdx.x;

    // ---------------- phase 1: sampling params for all items ----------------
    for (int it = t; it < NCAMS*192; it += 256) {
        int cam = it / 192;
        int r   = it - cam*192;          // h*24 + lvl*8 + p
        int hh  = r / 24;
        int rr  = r - hh*24;
        int lvl = rr >> 3;

        float mk = maskf[cam*NQ + n];
        float cx = coor[(cam*NQ + n)*2 + 0];
        float cy = coor[(cam*NQ + n)*2 + 1];
        float2 o2 = *reinterpret_cast<const float2*>(offs + (size_t)n*384 + r*2);
        float aw = (float)attn[(size_t)n*192 + r] * mk;

        int wi   = (lvl == 0) ? 176 : ((lvl == 1) ? 88 : 44);
        int hi   = (lvl == 0) ? 64  : ((lvl == 1) ? 32 : 16);
        int base = (lvl == 0) ? 0   : ((lvl == 1) ? 11264 : 14080);

        float x = cx*(float)wi + o2.x - 0.5f;
        float y = cy*(float)hi + o2.y - 0.5f;
        float xf = floorf(x), yf = floorf(y);
        float tx = x - xf, ty = y - yf;
        float wm1x = (float)(wi-1), wm1y = (float)(hi-1);
        bool vx0 = (xf >= 0.f)      && (xf <= wm1x);
        bool vx1 = (xf+1.f >= 0.f)  && (xf+1.f <= wm1x);
        bool vy0 = (yf >= 0.f)      && (yf <= wm1y);
        bool vy1 = (yf+1.f >= 0.f)  && (yf+1.f <= wm1y);
        int x0 = (int)fminf(fmaxf(xf,      0.f), wm1x);
        int x1 = (int)fminf(fmaxf(xf+1.f,  0.f), wm1x);
        int y0 = (int)fminf(fmaxf(yf,      0.f), wm1y);
        int y1 = (int)fminf(fmaxf(yf+1.f,  0.f), wm1y);
        float w00 = (1.f-tx)*(1.f-ty)*aw * ((vx0 && vy0) ? 1.f : 0.f);
        float w10 = tx*(1.f-ty)*aw       * ((vx1 && vy0) ? 1.f : 0.f);
        float w01 = (1.f-tx)*ty*aw       * ((vx0 && vy1) ? 1.f : 0.f);
        float w11 = tx*ty*aw             * ((vx1 && vy1) ? 1.f : 0.f);
        int rowb = (cam*NH + hh)*S_TOT + base;
        int r0 = rowb + y0*wi, r1 = rowb + y1*wi;
        s_o[it] = make_int2((r0 + x0)*64 + (x1 - x0), (r1 + x0)*64);
#if MSDA_DOT2
        bf16x2 wa; wa[0] = (bf16)w00; wa[1] = (bf16)w10;
        bf16x2 wb; wb[0] = (bf16)w01; wb[1] = (bf16)w11;
        s_w[it] = make_uint2(__builtin_bit_cast(unsigned, wa),
                             __builtin_bit_cast(unsigned, wb));
#else
        s_w[it] = (f32x4){w00, w10, w01, w11};
#endif
    }
    __syncthreads();

    // ---------------- phase 2: gather ----------------
    int lane = t & 63, wv = t >> 6;
    int hl = lane >> 5;              // 0..1
    int p  = (lane >> 2) & 7;        // 0..7
    int k2 = lane & 3;               // 0..3 -> 16B chunk of 64B row
    int hglob = wv*2 + hl;
    int kb = k2 * 16;
    int ibase = hglob*24 + p;

    f32x4 acc0 = (f32x4){0.f,0.f,0.f,0.f};
    f32x4 acc1 = (f32x4){0.f,0.f,0.f,0.f};
    const char* vbyte = (const char*)value;

    #pragma unroll 2
    for (int cam = 0; cam < NCAMS; cam++) {
        #pragma unroll
        for (int lvl = 0; lvl < 3; lvl++) {
            int it = cam*192 + ibase + lvl*8;
            int2 ov = s_o[it];
            int s2  = ov.x & 1;
            int dx  = s2 << 6;
            int a00 = (ov.x - s2) + kb;
            int a10 = a00 + dx;
            int a01 = ov.y + kb;
            int a11 = a01 + dx;
#if MSDA_DOT2
            uint2 wp = s_w[it];
            bf16x2 wa = __builtin_bit_cast(bf16x2, wp.x);
            bf16x2 wb = __builtin_bit_cast(bf16x2, wp.y);
            uint4 d00 = *reinterpret_cast<const uint4*>(vbyte + a00);
            uint4 d10 = *reinterpret_cast<const uint4*>(vbyte + a10);
            uint4 d01 = *reinterpret_cast<const uint4*>(vbyte + a01);
            uint4 d11 = *reinterpret_cast<const uint4*>(vbyte + a11);
            // corners (00,10) with wa
            unsigned a0 = __builtin_amdgcn_perm(d10.x, d00.x, 0x05040100u);
            unsigned a1 = __builtin_amdgcn_perm(d10.x, d00.x, 0x07060302u);
            unsigned a2 = __builtin_amdgcn_perm(d10.y, d00.y, 0x05040100u);
            unsigned a3 = __builtin_amdgcn_perm(d10.y, d00.y, 0x07060302u);
            unsigned a4 = __builtin_amdgcn_perm(d10.z, d00.z, 0x05040100u);
            unsigned a5 = __builtin_amdgcn_perm(d10.z, d00.z, 0x07060302u);
            unsigned a6 = __builtin_amdgcn_perm(d10.w, d00.w, 0x05040100u);
            unsigned a7 = __builtin_amdgcn_perm(d10.w, d00.w, 0x07060302u);
            acc0[0] = __builtin_amdgcn_fdot2_f32_bf16(__builtin_bit_cast(bf16x2, a0), wa, acc0[0], false);
            acc0[1] = __builtin_amdgcn_fdot2_f32_bf16(__builtin_bit_cast(bf16x2, a1), wa, acc0[1], false);
            acc0[2] = __builtin_amdgcn_fdot2_f32_bf16(__builtin_bit_cast(bf16x2, a2), wa, acc0[2], false);
            acc0[3] = __builtin_amdgcn_fdot2_f32_bf16(__builtin_bit_cast(bf16x2, a3), wa, acc0[3], false);
            acc1[0] = __builtin_amdgcn_fdot2_f32_bf16(__builtin_bit_cast(bf16x2, a4), wa, acc1[0], false);
            acc1[1] = __builtin_amdgcn_fdot2_f32_bf16(__builtin_bit_cast(bf16x2, a5), wa, acc1[1], false);
            acc1[2] = __builtin_amdgcn_fdot2_f32_bf16(__builtin_bit_cast(bf16x2, a6), wa, acc1[2], false);
            acc1[3] = __builtin_amdgcn_fdot2_f32_bf16(__builtin_bit_cast(bf16x2, a7), wa, acc1[3], false);
            // corners (01,11) with wb
            unsigned b0 = __builtin_amdgcn_perm(d11.x, d01.x, 0x05040100u);
            unsigned b1 = __builtin_amdgcn_perm(d11.x, d01.x, 0x07060302u);
            unsigned b2 = __builtin_amdgcn_perm(d11.y, d01.y, 0x05040100u);
            unsigned b3 = __builtin_amdgcn_perm(d11.y, d01.y, 0x07060302u);
            unsigned b4 = __builtin_amdgcn_perm(d11.z, d01.z, 0x05040100u);
            unsigned b5 = __builtin_amdgcn_perm(d11.z, d01.z, 0x07060302u);
            unsigned b6 = __builtin_amdgcn_perm(d11.w, d01.w, 0x05040100u);
            unsigned b7 = __builtin_amdgcn_perm(d11.w, d01.w, 0x07060302u);
            acc0[0] = __builtin_amdgcn_fdot2_f32_bf16(__builtin_bit_cast(bf16x2, b0), wb, acc0[0], false);
            acc0[1] = __builtin_amdgcn_fdot2_f32_bf16(__builtin_bit_cast(bf16x2, b1), wb, acc0[1], false);
            acc0[2] = __builtin_amdgcn_fdot2_f32_bf16(__builtin_bit_cast(bf16x2, b2), wb, acc0[2], false);
            acc0[3] = __builtin_amdgcn_fdot2_f32_bf16(__builtin_bit_cast(bf16x2, b3), wb, acc0[3], false);
            acc1[0] = __builtin_amdgcn_fdot2_f32_bf16(__builtin_bit_cast(bf16x2, b4), wb, acc1[0], false);
            acc1[1] = __builtin_amdgcn_fdot2_f32_bf16(__builtin_bit_cast(bf16x2, b5), wb, acc1[1], false);
            acc1[2] = __builtin_amdgcn_fdot2_f32_bf16(__builtin_bit_cast(bf16x2, b6), wb, acc1[2], false);
            acc1[3] = __builtin_amdgcn_fdot2_f32_bf16(__builtin_bit_cast(bf16x2, b7), wb, acc1[3], false);
#else
            f32x4 w4 = s_w[it];
            uint4 d00 = *reinterpret_cast<const uint4*>(vbyte + a00);
            uint4 d10 = *reinterpret_cast<const uint4*>(vbyte + a10);
            uint4 d01 = *reinterpret_cast<const uint4*>(vbyte + a01);
            uint4 d11 = *reinterpret_cast<const uint4*>(vbyte + a11);
            acc0[0] = fmaf(__uint_as_float(d00.x << 16),         w4.x, acc0[0]);
            acc0[1] = fmaf(__uint_as_float(d00.x & 0xffff0000u), w4.x, acc0[1]);
            acc0[2] = fmaf(__uint_as_float(d00.y << 16),         w4.x, acc0[2]);
            acc0[3] = fmaf(__uint_as_float(d00.y & 0xffff0000u), w4.x, acc0[3]);
            acc1[0] = fmaf(__uint_as_float(d00.z << 16),         w4.x, acc1[0]);
            acc1[1] = fmaf(__uint_as_float(d00.z & 0xffff0000u), w4.x, acc1[1]);
            acc1[2] = fmaf(__uint_as_float(d00.w << 16),         w4.x, acc1[2]);
            acc1[3] = fmaf(__uint_as_float(d00.w & 0xffff0000u), w4.x, acc1[3]);
            acc0[0] = fmaf(__uint_as_float(d10.x << 16),         w4.y, acc0[0]);
            acc0[1] = fmaf(__uint_as_float(d10.x & 0xffff0000u), w4.y, acc0[1]);
            acc0[2] = fmaf(__uint_as_float(d10.y << 16),         w4.y, acc0[2]);
            acc0[3] = fmaf(__uint_as_float(d10.y & 0xffff0000u), w4.y, acc0[3]);
            acc1[0] = fmaf(__uint_as_float(d10.z << 16),         w4.y, acc1[0]);
            acc1[1] = fmaf(__uint_as_float(d10.z & 0xffff0000u), w4.y, acc1[1]);
            acc1[2] = fmaf(__uint_as_float(d10.w << 16),         w4.y, acc1[2]);
            acc1[3] = fmaf(__uint_as_float(d10.w & 0xffff0000u), w4.y, acc1[3]);
            acc0[0] = fmaf(__uint_as_float(d01.x << 16),         w4.z, acc0[0]);
            acc0[1] = fmaf(__uint_as_float(d01.x & 0xffff0000u), w4.z, acc0[1]);
            acc0[2] = fmaf(__uint_as_float(d01.y << 16),         w4.z, acc0[2]);
            acc0[3] = fmaf(__uint_as_float(d01.y & 0xffff0000u), w4.z, acc0[3]);
            acc1[0] = fmaf(__uint_as_float(d01.z << 16),         w4.z, acc1[0]);
            acc1[1] = fmaf(__uint_as_float(d01.z & 0xffff0000u), w4.z, acc1[1]);
            acc1[2] = fmaf(__uint_as_float(d01.w << 16),         w4.z, acc1[2]);
            acc1[3] = fmaf(__uint_as_float(d01.w & 0xffff0000u), w4.z, acc1[3]);
            acc0[0] = fmaf(__uint_as_float(d11.x << 16),         w4.w, acc0[0]);
            acc0[1] = fmaf(__uint_as_float(d11.x & 0xffff0000u), w4.w, acc0[1]);
            acc0[2] = fmaf(__uint_as_float(d11.y << 16),         w4.w, acc0[2]);
            acc0[3] = fmaf(__uint_as_float(d11.y & 0xffff0000u), w4.w, acc0[3]);
            acc1[0] = fmaf(__uint_as_float(d11.z << 16),         w4.w, acc1[0]);
            acc1[1] = fmaf(__uint_as_float(d11.z & 0xffff0000u), w4.w, acc1[1]);
            acc1[2] = fmaf(__uint_as_float(d11.w << 16),         w4.w, acc1[2]);
            acc1[3] = fmaf(__uint_as_float(d11.w & 0xffff0000u), w4.w, acc1[3]);
#endif
        }
    }

    // reduce over p (lane bits 2..4)
    #pragma unroll
    for (int i = 0; i < 4; i++) {
        acc0[i] += __shfl_xor(acc0[i], 4);
        acc0[i] += __shfl_xor(acc0[i], 8);
        acc0[i] += __shfl_xor(acc0[i], 16);
        acc1[i] += __shfl_xor(acc1[i], 4);
        acc1[i] += __shfl_xor(acc1[i], 8);
        acc1[i] += __shfl_xor(acc1[i], 16);
    }
    if (p == 0) {
        float* dst = slots + (size_t)n*CH + hglob*32 + k2*8;
        *reinterpret_cast<f32x4*>(dst)     = acc0;
        *reinterpret_cast<f32x4*>(dst + 4) = acc1;
    }
}

// ---------------------------------------------------------------- K6: mask-mean + out proj (MFMA) + residual + LN
// 400 blocks x 16 queries; mask-mean folded into A-frag scale; fused LN.
__global__ __launch_bounds__(256) void k_final2(
    const float* __restrict__ slots, const float* __restrict__ maskf,
    const bf16* __restrict__ Wop, const float* __restrict__ b_out,
    const float* __restrict__ feature, const float* __restrict__ ln_g,
    const float* __restrict__ ln_b, float* __restrict__ out)
{
    __shared__ float yb[16][264];    // y rows, padded (264) for conflict-free scattered writes
    int t = threadIdx.x, lane = t & 63, w = t >> 6;
    int q = lane >> 4, r16 = lane & 15;
    int n0 = blockIdx.x * 16;

    float msum = 0.f;
    #pragma unroll
    for (int cam = 0; cam < NCAMS; cam++) msum += maskf[cam*NQ + n0 + r16];
    float inv = 1.f / fmaxf(msum, 1.f);

    f32x4 acc[4];
    #pragma unroll
    for (int i = 0; i < 4; i++) acc[i] = (f32x4){0.f,0.f,0.f,0.f};

    const float* srow = slots + (size_t)(n0 + r16)*CH;
    for (int kc = 0; kc < 8; kc++) {
        f32x4 a0 = *reinterpret_cast<const f32x4*>(srow + kc*32 + q*8);
        f32x4 a1 = *reinterpret_cast<const f32x4*>(srow + kc*32 + q*8 + 4);
        bf16x8 afr;
        #pragma unroll
        for (int i = 0; i < 4; i++) { afr[i] = (bf16)(a0[i]*inv); afr[4+i] = (bf16)(a1[i]*inv); }
        #pragma unroll
        for (int nf = 0; nf < 4; nf++) {
            bf16x8 bfr = *reinterpret_cast<const bf16x8*>(Wop + ((size_t)(kc*16 + w*4 + nf)*64 + lane)*8);
            acc[nf] = __builtin_amdgcn_mfma_f32_16x16x32_bf16(afr, bfr, acc[nf], 0, 0, 0);
        }
    }
    #pragma unroll
    for (int nf = 0; nf < 4; nf++) {
        int c = (w*4 + nf)*16 + r16;
        float bias = b_out[c];
        #pragma unroll
        for (int r = 0; r < 4; r++) {
            int m = q*4 + r;
            yb[m][c] = acc[nf][r] + bias + feature[(size_t)(n0+m)*CH + c];
        }
    }
    __syncthreads();
    // LN: row = t>>4 (16 rows), l16 = t&15 each sums 16 elements
    int row = t >> 4, l16 = t & 15;
    int c0 = l16 * 16;
    float s = 0.f, s2 = 0.f;
    #pragma unroll
    for (int j = 0; j < 16; j++) {
        float v = yb[row][c0 + j];
        s += v; s2 += v*v;
    }
    #pragma unroll
    for (int off = 1; off < 16; off <<= 1) {
        s  += __shfl_xor(s, off);
        s2 += __shfl_xor(s2, off);
    }
    float mu = s / 256.f;
    float rsig = rsqrtf(s2 / 256.f - mu*mu + 1e-5f);
    float* orow = out + (size_t)(n0 + row)*CH + c0;
    #pragma unroll
    for (int j4 = 0; j4 < 4; j4++) {
        f32x4 o;
        #pragma unroll
        for (int i = 0; i < 4; i++) {
            int c = c0 + j4*4 + i;
            o[i] = (yb[row][c] - mu) * rsig * ln_g[c] + ln_b[c];
        }
        *reinterpret_cast<f32x4*>(orow + j4*4) = o;
    }
}

// ---------------------------------------------------------------- launch
extern "C" void kernel_launch(void* const* d_in, const int* in_sizes, int n_in,
                              void* d_out, int out_size, void* d_ws, size_t ws_size,
                              hipStream_t stream)
{
    const float* means       = (const float*)d_in[0];
    const float* feature     = (const float*)d_in[1];
    const float* feat0       = (const float*)d_in[2];
    const float* feat1       = (const float*)d_in[3];
    const float* feat2       = (const float*)d_in[4];
    const float* cam2ego     = (const float*)d_in[5];
    const float* intrins     = (const float*)d_in[6];
    const float* post_rots   = (const float*)d_in[7];
    const float* post_trans  = (const float*)d_in[8];
    const float* W_off       = (const float*)d_in[9];
    const float* b_off       = (const float*)d_in[10];
    const float* W_attn      = (const float*)d_in[11];
    const float* b_attn      = (const float*)d_in[12];
    const float* W_val       = (const float*)d_in[13];
    const float* b_val       = (const float*)d_in[14];
    const float* W_out       = (const float*)d_in[15];
    const float* b_out       = (const float*)d_in[16];
    const float* cams_embeds = (const float*)d_in[17];
    const float* level_embeds= (const float*)d_in[18];
    const float* ln_g        = (const float*)d_in[19];
    const float* ln_b        = (const float*)d_in[20];
    const int*   img_h       = (const int*)d_in[21];
    const int*   img_w       = (const int*)d_in[22];

    // workspace layout (total 65,275,904 B = 62.3 MiB)
    char* ws = (char*)d_ws;
    float* coor  = (float*)(ws + 0);           //  6*6400*2 f32      =   307,200
    float* maskf = (float*)(ws + 307200);      //  6*6400 f32        =   153,600
    float* offs  = (float*)(ws + 460800);      //  6400*384 f32      = 9,830,400
    bf16*  attn  = (bf16*) (ws + 10291200);    //  6400*192 bf16     = 2,457,600
    bf16*  Wvp   = (bf16*) (ws + 12748800);    //  256*256 bf16      =   131,072
    bf16*  Woap  = (bf16*) (ws + 12879872);    //  256*576 bf16      =   294,912
    bf16*  Wop   = (bf16*) (ws + 13174784);    //  256*256 bf16      =   131,072
    float* slots = (float*)(ws + 13305856);    //  6400*256 f32      = 6,553,600
    bf16*  value = (bf16*) (ws + 19859456);    //  6*8*14784*32 bf16 = 45,416,448
    if (ws_size < 65275904u) return;

    k_prep    <<<286, 256, 0, stream>>>(means, cam2ego, intrins, post_rots, post_trans,
                                        img_h, img_w, W_val, W_off, W_attn, W_out,
                                        coor, maskf, Wvp, Woap, Wop);
    k_offattn2<<<400, 256, 0, stream>>>(feature, Woap, b_off, b_attn, offs, attn);
    k_valproj <<<1386, 256, 0, stream>>>(feat0, feat1, feat2, cams_embeds, level_embeds, Wvp, b_val, value);
    k_msda    <<<6400, 256, 0, stream>>>(coor, offs, attn, value, maskf, slots);
    k_final2  <<<400, 256, 0, stream>>>(slots, maskf, Wop, b_out, feature, ln_g, ln_b, (float*)d_out);
}

// Round 3
// 300.668 us; speedup vs baseline: 1.0173x; 1.0173x over previous
//
#include <hip/hip_runtime.h>
#include <hip/hip_bf16.h>

typedef __bf16 bf16;
typedef __attribute__((ext_vector_type(4))) float f32x4;
typedef __attribute__((ext_vector_type(8))) bf16 bf16x8;
typedef __attribute__((ext_vector_type(2))) bf16 bf16x2;

#define NCAMS 6
#define NQ 6400
#define CH 256
#define NH 8
#define NL 3
#define NP 8
#define S_TOT 14784   // 64*176 + 32*88 + 16*44

#if __has_builtin(__builtin_amdgcn_fdot2_f32_bf16) && __has_builtin(__builtin_amdgcn_perm)
#define MSDA_DOT2 1
#else
#define MSDA_DOT2 0
#endif

// ---------------------------------------------------------------- K1: prep = projection + weight packs
// blocks 0..149: projection; blocks 150..285: pack Wvp (8192) / Woap (18432) / Wop (8192)
__global__ __launch_bounds__(256) void k_prep(
    const float* __restrict__ means, const float* __restrict__ cam2ego,
    const float* __restrict__ intrins, const float* __restrict__ post_rots,
    const float* __restrict__ post_trans, const int* __restrict__ img_h,
    const int* __restrict__ img_w,
    const float* __restrict__ W_val, const float* __restrict__ W_off,
    const float* __restrict__ W_attn, const float* __restrict__ W_out,
    float* __restrict__ coor, float* __restrict__ maskf,
    bf16* __restrict__ Wvp, bf16* __restrict__ Woap, bf16* __restrict__ Wop)
{
    int bid = blockIdx.x;
    if (bid < 150) {
        int idx = bid * 256 + threadIdx.x;
        if (idx >= NCAMS * NQ) return;
        int cam = idx / NQ, n = idx % NQ;
        float mx = means[n*3+0], my = means[n*3+1], mz = means[n*3+2];
        const float* M = cam2ego + cam*16;
        float R[3][3], t[3];
        #pragma unroll
        for (int r = 0; r < 3; r++) {
            #pragma unroll
            for (int c = 0; c < 3; c++) R[r][c] = M[r*4+c];
            t[r] = M[r*4+3];
        }
        float dx = mx - t[0], dy = my - t[1], dz = mz - t[2];
        float xc = R[0][0]*dx + R[1][0]*dy + R[2][0]*dz;
        float yc = R[0][1]*dx + R[1][1]*dy + R[2][1]*dz;
        float zc = R[0][2]*dx + R[1][2]*dy + R[2][2]*dz;
        const float* K = intrins + cam*9;
        float ix = K[0]*xc + K[1]*yc + K[2]*zc;
        float iy = K[3]*xc + K[4]*yc + K[5]*zc;
        float iz = K[6]*xc + K[7]*yc + K[8]*zc;
        float px = ix / (iz + 1e-4f), py = iy / (iz + 1e-4f), pz = iz;
        const float* P = post_rots + cam*9;
        const float* T = post_trans + cam*3;
        float vx = P[0]*px + P[1]*py + P[2]*pz + T[0];
        float vy = P[3]*px + P[4]*py + P[5]*pz + T[1];
        float vz = P[6]*px + P[7]*py + P[8]*pz + T[2];
        float cx = vx / (float)img_w[0];
        float cy = vy / (float)img_h[0];
        bool ok = (vz > 0.01f) && (cx > 0.f) && (cx < 1.f) && (cy > 0.f) && (cy < 1.f);
        coor[idx*2+0] = cx;
        coor[idx*2+1] = cy;
        maskf[idx] = ok ? 1.f : 0.f;
        return;
    }
    int flat = (bid - 150) * 256 + threadIdx.x;
    if (flat < 8192) {
        // Wvp: (kc*16+nf)*64+lane <- W_val[kc*32+q*8+j][nf*16+l15]
        int kc = flat >> 10, rem = flat & 1023;
        int nf = rem >> 6, lane = rem & 63;
        int q = lane >> 4, col = nf*16 + (lane & 15);
        bf16x8 v;
        #pragma unroll
        for (int j = 0; j < 8; j++) v[j] = (bf16)W_val[(size_t)(kc*32 + q*8 + j)*256 + col];
        *reinterpret_cast<bf16x8*>(Wvp + (size_t)flat*8) = v;
    } else if (flat < 26624) {
        // Woap: 576 logical cols = [W_off 0..383 | W_attn 384..575]
        int f2 = flat - 8192;
        int kc = f2 / (36*64), rem = f2 % (36*64);
        int nf = rem >> 6, lane = rem & 63;
        int q = lane >> 4, col = nf*16 + (lane & 15);
        bf16x8 v;
        #pragma unroll
        for (int j = 0; j < 8; j++) {
            int k = kc*32 + q*8 + j;
            float x = (col < 384) ? W_off[(size_t)k*384 + col] : W_attn[(size_t)k*192 + (col-384)];
            v[j] = (bf16)x;
        }
        *reinterpret_cast<bf16x8*>(Woap + (size_t)f2*8) = v;
    } else if (flat < 34816) {
        int f3 = flat - 26624;
        int kc = f3 >> 10, rem = f3 & 1023;
        int nf = rem >> 6, lane = rem & 63;
        int q = lane >> 4, col = nf*16 + (lane & 15);
        bf16x8 v;
        #pragma unroll
        for (int j = 0; j < 8; j++) v[j] = (bf16)W_out[(size_t)(kc*32 + q*8 + j)*256 + col];
        *reinterpret_cast<bf16x8*>(Wop + (size_t)f3*8) = v;
    }
}

// ---------------------------------------------------------------- K2: offsets + attn via MFMA (+softmax)
// 400 blocks x 16 queries. A-frags direct from global (feature rows are k-contiguous).
__global__ __launch_bounds__(256) void k_offattn2(
    const float* __restrict__ feature, const bf16* __restrict__ Woap,
    const float* __restrict__ b_off, const float* __restrict__ b_attn,
    float* __restrict__ offs, bf16* __restrict__ attn_out)
{
    __shared__ float lg[16][200];    // logits [m][192], padded
    int t = threadIdx.x, lane = t & 63, w = t >> 6;
    int q = lane >> 4, r16 = lane & 15;
    int n0 = blockIdx.x * 16;

    f32x4 acc[9];
    #pragma unroll
    for (int i = 0; i < 9; i++) acc[i] = (f32x4){0.f,0.f,0.f,0.f};

    const float* arow = feature + (size_t)(n0 + r16)*CH;
    for (int kc = 0; kc < 8; kc++) {
        f32x4 a0 = *reinterpret_cast<const f32x4*>(arow + kc*32 + q*8);
        f32x4 a1 = *reinterpret_cast<const f32x4*>(arow + kc*32 + q*8 + 4);
        bf16x8 afr;
        #pragma unroll
        for (int i = 0; i < 4; i++) { afr[i] = (bf16)a0[i]; afr[4+i] = (bf16)a1[i]; }
        #pragma unroll
        for (int nf9 = 0; nf9 < 9; nf9++) {
            bf16x8 bfr = *reinterpret_cast<const bf16x8*>(Woap + ((size_t)(kc*36 + w*9 + nf9)*64 + lane)*8);
            acc[nf9] = __builtin_amdgcn_mfma_f32_16x16x32_bf16(afr, bfr, acc[nf9], 0, 0, 0);
        }
    }
    #pragma unroll
    for (int nf9 = 0; nf9 < 9; nf9++) {
        int nfg = w*9 + nf9;
        int nglob = nfg*16 + r16;
        if (nfg < 24) {                       // offsets (wave-uniform branch)
            float bias = b_off[nglob];
            #pragma unroll
            for (int r = 0; r < 4; r++)
                offs[(size_t)(n0 + q*4 + r)*384 + nglob] = acc[nf9][r] + bias;
        } else {                              // attn logits -> LDS
            int la = nglob - 384;
            float bias = b_attn[la];
            #pragma unroll
            for (int r = 0; r < 4; r++)
                lg[q*4 + r][la] = acc[nf9][r] + bias;
        }
    }
    __syncthreads();
    if (t < 128) {
        int m = t >> 3, h = t & 7;
        const float* L = &lg[m][h*24];
        float mx = -1e30f;
        #pragma unroll
        for (int j = 0; j < 24; j++) mx = fmaxf(mx, L[j]);
        float e[24]; float s = 0.f;
        #pragma unroll
        for (int j = 0; j < 24; j++) { e[j] = __expf(L[j] - mx); s += e[j]; }
        float inv = 1.f / s;
        #pragma unroll
        for (int j = 0; j < 24; j++) attn_out[(size_t)(n0+m)*192 + h*24 + j] = (bf16)(e[j]*inv);
    }
}

// ---------------------------------------------------------------- K3: value projection GEMM (MFMA bf16)
// value layout: [cam][head][pos][32ch]  (bf16)
__global__ __launch_bounds__(256) void k_valproj(
    const float* __restrict__ f0, const float* __restrict__ f1, const float* __restrict__ f2,
    const float* __restrict__ cams_embeds, const float* __restrict__ level_embeds,
    const bf16* __restrict__ Wvp, const float* __restrict__ b_val, bf16* __restrict__ value)
{
    __shared__ alignas(16) bf16 A[64][48];    // [m][k], padded row 48 (6144 B)
    __shared__ alignas(16) bf16 Cst[16][256]; // epilogue staging stripe (8192 B)
    int bi = blockIdx.x;
    int cam = bi / 231, mb = bi % 231;
    int lvl, local0, HW;
    const float* fp;
    if (mb < 176)      { lvl = 0; local0 = mb*64;        fp = f0; HW = 11264; }
    else if (mb < 220) { lvl = 1; local0 = (mb-176)*64;  fp = f1; HW = 2816;  }
    else               { lvl = 2; local0 = (mb-220)*64;  fp = f2; HW = 704;   }
    int pos0 = (lvl == 0 ? 0 : (lvl == 1 ? 11264 : 14080)) + local0;
    const float* featbase = fp + (size_t)cam*CH*HW + local0;

    int t = threadIdx.x;
    int lane = t & 63, w = t >> 6;
    int kk = t >> 3;            // 0..31 (channel within chunk)
    int m8 = (t & 7) * 8;       // m start
    int q = lane >> 4, r16 = lane & 15;

    f32x4 acc[4][4];
    #pragma unroll
    for (int i = 0; i < 4; i++)
        #pragma unroll
        for (int j = 0; j < 4; j++) acc[i][j] = (f32x4){0.f,0.f,0.f,0.f};

    for (int kc = 0; kc < 8; kc++) {
        __syncthreads();
        int kg = kc*32 + kk;
        float e = cams_embeds[cam*CH + kg] + level_embeds[lvl*CH + kg];
        f32x4 v0 = *reinterpret_cast<const f32x4*>(featbase + (size_t)kg*HW + m8);
        f32x4 v1 = *reinterpret_cast<const f32x4*>(featbase + (size_t)kg*HW + m8 + 4);
        #pragma unroll
        for (int i = 0; i < 4; i++) A[m8+i][kk]   = (bf16)(v0[i] + e);
        #pragma unroll
        for (int i = 0; i < 4; i++) A[m8+4+i][kk] = (bf16)(v1[i] + e);
        __syncthreads();

        bf16x8 bfr[4];
        #pragma unroll
        for (int nf = 0; nf < 4; nf++) {
            int nfg = w*4 + nf;
            bfr[nf] = *reinterpret_cast<const bf16x8*>(Wvp + ((size_t)(kc*16 + nfg)*64 + lane)*8);
        }
        #pragma unroll
        for (int mf = 0; mf < 4; mf++) {
            bf16x8 afr = *reinterpret_cast<const bf16x8*>(&A[mf*16 + r16][q*8]);
            #pragma unroll
            for (int nf = 0; nf < 4; nf++)
                acc[mf][nf] = __builtin_amdgcn_mfma_f32_16x16x32_bf16(afr, bfr[nf], acc[mf][nf], 0, 0, 0);
        }
    }
    // epilogue, per 16-row stripe -> LDS -> coalesced 16B stores
    int orow = t >> 4;                // 0..15
    int ocol = (t & 15) * 16;         // 0..240 step 16
    int ohead = ocol >> 5, och = ocol & 31;
    #pragma unroll
    for (int mf = 0; mf < 4; mf++) {
        __syncthreads();
        #pragma unroll
        for (int nf = 0; nf < 4; nf++) {
            int c = w*64 + nf*16 + r16;
            float bv = b_val[c];
            #pragma unroll
            for (int r = 0; r < 4; r++)
                Cst[q*4 + r][c] = (bf16)(acc[mf][nf][r] + bv);
        }
        __syncthreads();
        int srow = pos0 + mf*16 + orow;
        bf16* dst = value + ((size_t)(cam*NH + ohead)*S_TOT + srow)*32 + och;
        const f32x4* src = reinterpret_cast<const f32x4*>(&Cst[orow][ocol]);
        f32x4 x0 = src[0], x1 = src[1];
        reinterpret_cast<f32x4*>(dst)[0] = x0;
        reinterpret_cast<f32x4*>(dst)[1] = x1;
    }
}

// ---------------------------------------------------------------- K4: MSDA gather
// Phase 1: sampling params for ALL 6 cams x 8 heads x 24 (lvl,pt) -> LDS, mask folded into weights.
// Phase 2 (R3): per-cam batched gather. All 12 corner loads of a cam (3 lvls x 4 corners) issue
// as one batch; next cam's LDS params prefetch into registers before the perm/fdot chain; cam loop
// fully unrolled so the scheduler can hoist cam c+1's loads above cam c's consume. Rationale:
// R2 showed +50% occupancy = 0 speedup at HBM 30% / L2 ~19 TB/s -> not BW-bound; Little's law on
// 7200 loads/CU over 237K cy gives ~0.5 loads in flight per wave -> per-iteration latency chain
// (ds_read -> unpack -> 4 loads -> vmcnt(0) -> 32 VALU) is the bottleneck. MLP, not TLP.
__global__ __launch_bounds__(256) void k_msda(
    const float* __restrict__ coor, const float* __restrict__ offs,
    const bf16* __restrict__ attn, const bf16* __restrict__ value,
    const float* __restrict__ maskf, float* __restrict__ slots)
{
    // item = cam*192 + h*24 + lvl*8 + p
    __shared__ int2  s_o[NCAMS*192];     // {y0-row offset | dx bit, y1-row offset}  (9216 B)
#if MSDA_DOT2
    __shared__ uint2 s_w[NCAMS*192];     // packed bf16 {w00,w10},{w01,w11} (9216 B)
#else
    __shared__ f32x4 s_w[NCAMS*192];
#endif
    int n = blockIdx.x;
    int t = threadIdx.x;

    // ---------------- phase 1: sampling params for all items ----------------
    for (int it = t; it < NCAMS*192; it += 256) {
        int cam = it / 192;
        int r   = it - cam*192;          // h*24 + lvl*8 + p
        int hh  = r / 24;
        int rr  = r - hh*24;
        int lvl = rr >> 3;

        float mk = maskf[cam*NQ + n];
        float cx = coor[(cam*NQ + n)*2 + 0];
        float cy = coor[(cam*NQ + n)*2 + 1];
        float2 o2 = *reinterpret_cast<const float2*>(offs + (size_t)n*384 + r*2);
        float aw = (float)attn[(size_t)n*192 + r] * mk;

        int wi   = (lvl == 0) ? 176 : ((lvl == 1) ? 88 : 44);
        int hi   = (lvl == 0) ? 64  : ((lvl == 1) ? 32 : 16);
        int base = (lvl == 0) ? 0   : ((lvl == 1) ? 11264 : 14080);

        float x = cx*(float)wi + o2.x - 0.5f;
        float y = cy*(float)hi + o2.y - 0.5f;
        float xf = floorf(x), yf = floorf(y);
        float tx = x - xf, ty = y - yf;
        float wm1x = (float)(wi-1), wm1y = (float)(hi-1);
        bool vx0 = (xf >= 0.f)      && (xf <= wm1x);
        bool vx1 = (xf+1.f >= 0.f)  && (xf+1.f <= wm1x);
        bool vy0 = (yf >= 0.f)      && (yf <= wm1y);
        bool vy1 = (yf+1.f >= 0.f)  && (yf+1.f <= wm1y);
        int x0 = (int)fminf(fmaxf(xf,      0.f), wm1x);
        int x1 = (int)fminf(fmaxf(xf+1.f,  0.f), wm1x);
        int y0 = (int)fminf(fmaxf(yf,      0.f), wm1y);
        int y1 = (int)fminf(fmaxf(yf+1.f,  0.f), wm1y);
        float w00 = (1.f-tx)*(1.f-ty)*aw * ((vx0 && vy0) ? 1.f : 0.f);
        float w10 = tx*(1.f-ty)*aw       * ((vx1 && vy0) ? 1.f : 0.f);
        float w01 = (1.f-tx)*ty*aw       * ((vx0 && vy1) ? 1.f : 0.f);
        float w11 = tx*ty*aw             * ((vx1 && vy1) ? 1.f : 0.f);
        int rowb = (cam*NH + hh)*S_TOT + base;
        int r0 = rowb + y0*wi, r1 = rowb + y1*wi;
        s_o[it] = make_int2((r0 + x0)*64 + (x1 - x0), (r1 + x0)*64);
#if MSDA_DOT2
        bf16x2 wa; wa[0] = (bf16)w00; wa[1] = (bf16)w10;
        bf16x2 wb; wb[0] = (bf16)w01; wb[1] = (bf16)w11;
        s_w[it] = make_uint2(__builtin_bit_cast(unsigned, wa),
                             __builtin_bit_cast(unsigned, wb));
#else
        s_w[it] = (f32x4){w00, w10, w01, w11};
#endif
    }
    __syncthreads();

    // ---------------- phase 2: gather, per-cam batched ----------------
    int lane = t & 63, wv = t >> 6;
    int hl = lane >> 5;              // 0..1
    int p  = (lane >> 2) & 7;        // 0..7
    int k2 = lane & 3;               // 0..3 -> 16B chunk of 64B row
    int hglob = wv*2 + hl;
    int kb = k2 * 16;
    int ibase = hglob*24 + p;

    f32x4 acc0 = (f32x4){0.f,0.f,0.f,0.f};
    f32x4 acc1 = (f32x4){0.f,0.f,0.f,0.f};
    const char* vbyte = (const char*)value;

    // rolling params for current cam
    int2  co[3];
#if MSDA_DOT2
    uint2 cw[3];
#else
    f32x4 cw[3];
#endif
    #pragma unroll
    for (int l = 0; l < 3; l++) { co[l] = s_o[ibase + l*8]; cw[l] = s_w[ibase + l*8]; }

    #pragma unroll
    for (int cam = 0; cam < NCAMS; cam++) {
        // ---- issue all 12 corner loads for this cam (batch -> 12 in flight) ----
        uint4 d[3][4];
#if MSDA_DOT2
        uint2 wcur[3];
#else
        f32x4 wcur[3];
#endif
        #pragma unroll
        for (int l = 0; l < 3; l++) {
            int s2  = co[l].x & 1;
            int dx  = s2 << 6;
            int a00 = (co[l].x - s2) + kb;
            int a01 = co[l].y + kb;
            d[l][0] = *reinterpret_cast<const uint4*>(vbyte + a00);
            d[l][1] = *reinterpret_cast<const uint4*>(vbyte + (a00 + dx));
            d[l][2] = *reinterpret_cast<const uint4*>(vbyte + a01);
            d[l][3] = *reinterpret_cast<const uint4*>(vbyte + (a01 + dx));
            wcur[l] = cw[l];
        }
        // ---- prefetch next cam's LDS params (overlaps with loads above) ----
        if (cam + 1 < NCAMS) {
            int nb = (cam + 1)*192 + ibase;
            #pragma unroll
            for (int l = 0; l < 3; l++) { co[l] = s_o[nb + l*8]; cw[l] = s_w[nb + l*8]; }
        }
        // ---- consume ----
        #pragma unroll
        for (int l = 0; l < 3; l++) {
            uint4 d00 = d[l][0], d10 = d[l][1], d01 = d[l][2], d11 = d[l][3];
#if MSDA_DOT2
            bf16x2 wa = __builtin_bit_cast(bf16x2, wcur[l].x);
            bf16x2 wb = __builtin_bit_cast(bf16x2, wcur[l].y);
            unsigned a0 = __builtin_amdgcn_perm(d10.x, d00.x, 0x05040100u);
            unsigned a1 = __builtin_amdgcn_perm(d10.x, d00.x, 0x07060302u);
            unsigned a2 = __builtin_amdgcn_perm(d10.y, d00.y, 0x05040100u);
            unsigned a3 = __builtin_amdgcn_perm(d10.y, d00.y, 0x07060302u);
            unsigned a4 = __builtin_amdgcn_perm(d10.z, d00.z, 0x05040100u);
            unsigned a5 = __builtin_amdgcn_perm(d10.z, d00.z, 0x07060302u);
            unsigned a6 = __builtin_amdgcn_perm(d10.w, d00.w, 0x05040100u);
            unsigned a7 = __builtin_amdgcn_perm(d10.w, d00.w, 0x07060302u);
            acc0[0] = __builtin_amdgcn_fdot2_f32_bf16(__builtin_bit_cast(bf16x2, a0), wa, acc0[0], false);
            acc0[1] = __builtin_amdgcn_fdot2_f32_bf16(__builtin_bit_cast(bf16x2, a1), wa, acc0[1], false);
            acc0[2] = __builtin_amdgcn_fdot2_f32_bf16(__builtin_bit_cast(bf16x2, a2), wa, acc0[2], false);
            acc0[3] = __builtin_amdgcn_fdot2_f32_bf16(__builtin_bit_cast(bf16x2, a3), wa, acc0[3], false);
            acc1[0] = __builtin_amdgcn_fdot2_f32_bf16(__builtin_bit_cast(bf16x2, a4), wa, acc1[0], false);
            acc1[1] = __builtin_amdgcn_fdot2_f32_bf16(__builtin_bit_cast(bf16x2, a5), wa, acc1[1], false);
            acc1[2] = __builtin_amdgcn_fdot2_f32_bf16(__builtin_bit_cast(bf16x2, a6), wa, acc1[2], false);
            acc1[3] = __builtin_amdgcn_fdot2_f32_bf16(__builtin_bit_cast(bf16x2, a7), wa, acc1[3], false);
            unsigned b0 = __builtin_amdgcn_perm(d11.x, d01.x, 0x05040100u);
            unsigned b1 = __builtin_amdgcn_perm(d11.x, d01.x, 0x07060302u);
            unsigned b2 = __builtin_amdgcn_perm(d11.y, d01.y, 0x05040100u);
            unsigned b3 = __builtin_amdgcn_perm(d11.y, d01.y, 0x07060302u);
            unsigned b4 = __builtin_amdgcn_perm(d11.z, d01.z, 0x05040100u);
            unsigned b5 = __builtin_amdgcn_perm(d11.z, d01.z, 0x07060302u);
            unsigned b6 = __builtin_amdgcn_perm(d11.w, d01.w, 0x05040100u);
            unsigned b7 = __builtin_amdgcn_perm(d11.w, d01.w, 0x07060302u);
            acc0[0] = __builtin_amdgcn_fdot2_f32_bf16(__builtin_bit_cast(bf16x2, b0), wb, acc0[0], false);
            acc0[1] = __builtin_amdgcn_fdot2_f32_bf16(__builtin_bit_cast(bf16x2, b1), wb, acc0[1], false);
            acc0[2] = __builtin_amdgcn_fdot2_f32_bf16(__builtin_bit_cast(bf16x2, b2), wb, acc0[2], false);
            acc0[3] = __builtin_amdgcn_fdot2_f32_bf16(__builtin_bit_cast(bf16x2, b3), wb, acc0[3], false);
            acc1[0] = __builtin_amdgcn_fdot2_f32_bf16(__builtin_bit_cast(bf16x2, b4), wb, acc1[0], false);
            acc1[1] = __builtin_amdgcn_fdot2_f32_bf16(__builtin_bit_cast(bf16x2, b5), wb, acc1[1], false);
            acc1[2] = __builtin_amdgcn_fdot2_f32_bf16(__builtin_bit_cast(bf16x2, b6), wb, acc1[2], false);
            acc1[3] = __builtin_amdgcn_fdot2_f32_bf16(__builtin_bit_cast(bf16x2, b7), wb, acc1[3], false);
#else
            f32x4 w4 = wcur[l];
            acc0[0] = fmaf(__uint_as_float(d00.x << 16),         w4.x, acc0[0]);
            acc0[1] = fmaf(__uint_as_float(d00.x & 0xffff0000u), w4.x, acc0[1]);
            acc0[2] = fmaf(__uint_as_float(d00.y << 16),         w4.x, acc0[2]);
            acc0[3] = fmaf(__uint_as_float(d00.y & 0xffff0000u), w4.x, acc0[3]);
            acc1[0] = fmaf(__uint_as_float(d00.z << 16),         w4.x, acc1[0]);
            acc1[1] = fmaf(__uint_as_float(d00.z & 0xffff0000u), w4.x, acc1[1]);
            acc1[2] = fmaf(__uint_as_float(d00.w << 16),         w4.x, acc1[2]);
            acc1[3] = fmaf(__uint_as_float(d00.w & 0xffff0000u), w4.x, acc1[3]);
            acc0[0] = fmaf(__uint_as_float(d10.x << 16),         w4.y, acc0[0]);
            acc0[1] = fmaf(__uint_as_float(d10.x & 0xffff0000u), w4.y, acc0[1]);
            acc0[2] = fmaf(__uint_as_float(d10.y << 16),         w4.y, acc0[2]);
            acc0[3] = fmaf(__uint_as_float(d10.y & 0xffff0000u), w4.y, acc0[3]);
            acc1[0] = fmaf(__uint_as_float(d10.z << 16),         w4.y, acc1[0]);
            acc1[1] = fmaf(__uint_as_float(d10.z & 0xffff0000u), w4.y, acc1[1]);
            acc1[2] = fmaf(__uint_as_float(d10.w << 16),         w4.y, acc1[2]);
            acc1[3] = fmaf(__uint_as_float(d10.w & 0xffff0000u), w4.y, acc1[3]);
            acc0[0] = fmaf(__uint_as_float(d01.x << 16),         w4.z, acc0[0]);
            acc0[1] = fmaf(__uint_as_float(d01.x & 0xffff0000u), w4.z, acc0[1]);
            acc0[2] = fmaf(__uint_as_float(d01.y << 16),         w4.z, acc0[2]);
            acc0[3] = fmaf(__uint_as_float(d01.y & 0xffff0000u), w4.z, acc0[3]);
            acc1[0] = fmaf(__uint_as_float(d01.z << 16),         w4.z, acc1[0]);
            acc1[1] = fmaf(__uint_as_float(d01.z & 0xffff0000u), w4.z, acc1[1]);
            acc1[2] = fmaf(__uint_as_float(d01.w << 16),         w4.z, acc1[2]);
            acc1[3] = fmaf(__uint_as_float(d01.w & 0xffff0000u), w4.z, acc1[3]);
            acc0[0] = fmaf(__uint_as_float(d11.x << 16),         w4.w, acc0[0]);
            acc0[1] = fmaf(__uint_as_float(d11.x & 0xffff0000u), w4.w, acc0[1]);
            acc0[2] = fmaf(__uint_as_float(d11.y << 16),         w4.w, acc0[2]);
            acc0[3] = fmaf(__uint_as_float(d11.y & 0xffff0000u), w4.w, acc0[3]);
            acc1[0] = fmaf(__uint_as_float(d11.z << 16),         w4.w, acc1[0]);
            acc1[1] = fmaf(__uint_as_float(d11.z & 0xffff0000u), w4.w, acc1[1]);
            acc1[2] = fmaf(__uint_as_float(d11.w << 16),         w4.w, acc1[2]);
            acc1[3] = fmaf(__uint_as_float(d11.w & 0xffff0000u), w4.w, acc1[3]);
#endif
        }
    }

    // reduce over p (lane bits 2..4)
    #pragma unroll
    for (int i = 0; i < 4; i++) {
        acc0[i] += __shfl_xor(acc0[i], 4);
        acc0[i] += __shfl_xor(acc0[i], 8);
        acc0[i] += __shfl_xor(acc0[i], 16);
        acc1[i] += __shfl_xor(acc1[i], 4);
        acc1[i] += __shfl_xor(acc1[i], 8);
        acc1[i] += __shfl_xor(acc1[i], 16);
    }
    if (p == 0) {
        float* dst = slots + (size_t)n*CH + hglob*32 + k2*8;
        *reinterpret_cast<f32x4*>(dst)     = acc0;
        *reinterpret_cast<f32x4*>(dst + 4) = acc1;
    }
}

// ---------------------------------------------------------------- K6: mask-mean + out proj (MFMA) + residual + LN
// 400 blocks x 16 queries; mask-mean folded into A-frag scale; fused LN.
__global__ __launch_bounds__(256) void k_final2(
    const float* __restrict__ slots, const float* __restrict__ maskf,
    const bf16* __restrict__ Wop, const float* __restrict__ b_out,
    const float* __restrict__ feature, const float* __restrict__ ln_g,
    const float* __restrict__ ln_b, float* __restrict__ out)
{
    __shared__ float yb[16][264];    // y rows, padded (264) for conflict-free scattered writes
    int t = threadIdx.x, lane = t & 63, w = t >> 6;
    int q = lane >> 4, r16 = lane & 15;
    int n0 = blockIdx.x * 16;

    float msum = 0.f;
    #pragma unroll
    for (int cam = 0; cam < NCAMS; cam++) msum += maskf[cam*NQ + n0 + r16];
    float inv = 1.f / fmaxf(msum, 1.f);

    f32x4 acc[4];
    #pragma unroll
    for (int i = 0; i < 4; i++) acc[i] = (f32x4){0.f,0.f,0.f,0.f};

    const float* srow = slots + (size_t)(n0 + r16)*CH;
    for (int kc = 0; kc < 8; kc++) {
        f32x4 a0 = *reinterpret_cast<const f32x4*>(srow + kc*32 + q*8);
        f32x4 a1 = *reinterpret_cast<const f32x4*>(srow + kc*32 + q*8 + 4);
        bf16x8 afr;
        #pragma unroll
        for (int i = 0; i < 4; i++) { afr[i] = (bf16)(a0[i]*inv); afr[4+i] = (bf16)(a1[i]*inv); }
        #pragma unroll
        for (int nf = 0; nf < 4; nf++) {
            bf16x8 bfr = *reinterpret_cast<const bf16x8*>(Wop + ((size_t)(kc*16 + w*4 + nf)*64 + lane)*8);
            acc[nf] = __builtin_amdgcn_mfma_f32_16x16x32_bf16(afr, bfr, acc[nf], 0, 0, 0);
        }
    }
    #pragma unroll
    for (int nf = 0; nf < 4; nf++) {
        int c = (w*4 + nf)*16 + r16;
        float bias = b_out[c];
        #pragma unroll
        for (int r = 0; r < 4; r++) {
            int m = q*4 + r;
            yb[m][c] = acc[nf][r] + bias + feature[(size_t)(n0+m)*CH + c];
        }
    }
    __syncthreads();
    // LN: row = t>>4 (16 rows), l16 = t&15 each sums 16 elements
    int row = t >> 4, l16 = t & 15;
    int c0 = l16 * 16;
    float s = 0.f, s2 = 0.f;
    #pragma unroll
    for (int j = 0; j < 16; j++) {
        float v = yb[row][c0 + j];
        s += v; s2 += v*v;
    }
    #pragma unroll
    for (int off = 1; off < 16; off <<= 1) {
        s  += __shfl_xor(s, off);
        s2 += __shfl_xor(s2, off);
    }
    float mu = s / 256.f;
    float rsig = rsqrtf(s2 / 256.f - mu*mu + 1e-5f);
    float* orow = out + (size_t)(n0 + row)*CH + c0;
    #pragma unroll
    for (int j4 = 0; j4 < 4; j4++) {
        f32x4 o;
        #pragma unroll
        for (int i = 0; i < 4; i++) {
            int c = c0 + j4*4 + i;
            o[i] = (yb[row][c] - mu) * rsig * ln_g[c] + ln_b[c];
        }
        *reinterpret_cast<f32x4*>(orow + j4*4) = o;
    }
}

// ---------------------------------------------------------------- launch
extern "C" void kernel_launch(void* const* d_in, const int* in_sizes, int n_in,
                              void* d_out, int out_size, void* d_ws, size_t ws_size,
                              hipStream_t stream)
{
    const float* means       = (const float*)d_in[0];
    const float* feature     = (const float*)d_in[1];
    const float* feat0       = (const float*)d_in[2];
    const float* feat1       = (const float*)d_in[3];
    const float* feat2       = (const float*)d_in[4];
    const float* cam2ego     = (const float*)d_in[5];
    const float* intrins     = (const float*)d_in[6];
    const float* post_rots   = (const float*)d_in[7];
    const float* post_trans  = (const float*)d_in[8];
    const float* W_off       = (const float*)d_in[9];
    const float* b_off       = (const float*)d_in[10];
    const float* W_attn      = (const float*)d_in[11];
    const float* b_attn      = (const float*)d_in[12];
    const float* W_val       = (const float*)d_in[13];
    const float* b_val       = (const float*)d_in[14];
    const float* W_out       = (const float*)d_in[15];
    const float* b_out       = (const float*)d_in[16];
    const float* cams_embeds = (const float*)d_in[17];
    const float* level_embeds= (const float*)d_in[18];
    const float* ln_g        = (const float*)d_in[19];
    const float* ln_b        = (const float*)d_in[20];
    const int*   img_h       = (const int*)d_in[21];
    const int*   img_w       = (const int*)d_in[22];

    // workspace layout (total 65,275,904 B = 62.3 MiB)
    char* ws = (char*)d_ws;
    float* coor  = (float*)(ws + 0);           //  6*6400*2 f32      =   307,200
    float* maskf = (float*)(ws + 307200);      //  6*6400 f32        =   153,600
    float* offs  = (float*)(ws + 460800);      //  6400*384 f32      = 9,830,400
    bf16*  attn  = (bf16*) (ws + 10291200);    //  6400*192 bf16     = 2,457,600
    bf16*  Wvp   = (bf16*) (ws + 12748800);    //  256*256 bf16      =   131,072
    bf16*  Woap  = (bf16*) (ws + 12879872);    //  256*576 bf16      =   294,912
    bf16*  Wop   = (bf16*) (ws + 13174784);    //  256*256 bf16      =   131,072
    float* slots = (float*)(ws + 13305856);    //  6400*256 f32      = 6,553,600
    bf16*  value = (bf16*) (ws + 19859456);    //  6*8*14784*32 bf16 = 45,416,448
    if (ws_size < 65275904u) return;

    k_prep    <<<286, 256, 0, stream>>>(means, cam2ego, intrins, post_rots, post_trans,
                                        img_h, img_w, W_val, W_off, W_attn, W_out,
                                        coor, maskf, Wvp, Woap, Wop);
    k_offattn2<<<400, 256, 0, stream>>>(feature, Woap, b_off, b_attn, offs, attn);
    k_valproj <<<1386, 256, 0, stream>>>(feat0, feat1, feat2, cams_embeds, level_embeds, Wvp, b_val, value);
    k_msda    <<<6400, 256, 0, stream>>>(coor, offs, attn, value, maskf, slots);
    k_final2  <<<400, 256, 0, stream>>>(slots, maskf, Wop, b_out, feature, ln_g, ln_b, (float*)d_out);
}